// Round 10
// baseline (291.751 us; speedup 1.0000x reference)
//
#include <hip/hip_runtime.h>

// ---------------------------------------------------------------------------
// Two-layer GCN on MI355X.  Round 10 = R7 weight-form + R8 fusion + 1 node/wave.
//   w_e = dinv[s]*ew*dinv[d] precomputed in B2 -> feature rows stay RAW,
//   self-loop weight = dinv[d]^2 (register).  gemm1 is dinv-independent and
//   fuses into the a2 dispatch (overlap).  gg: 1024 thr, 16 waves, 1 node per
//   wave (full TLP) + in-block MFMA gemm2 on the 16-node g1 tile.
//   Pipeline: prepA1 -> scanB -> a2+gemm1 -> B1 -> B2 -> gg -> gather64
// ---------------------------------------------------------------------------

#define N_NODES 100000
#define CHUNK   2048
#define NBUCK   196
#define BSHIFT  9
#define BNODES  512
#define CAP     10240

typedef __attribute__((ext_vector_type(8))) short bf16x8;
typedef __attribute__((ext_vector_type(4))) float f32x4;

__device__ __forceinline__ unsigned bf16r(float f) {
    unsigned u = __float_as_uint(f);
    return (u + 0x7fffu + ((u >> 16) & 1u)) >> 16;     // RNE
}
__device__ __forceinline__ float bf_lo(unsigned u) { return __uint_as_float(u << 16); }
__device__ __forceinline__ float bf_hi(unsigned u) { return __uint_as_float(u & 0xffff0000u); }

// ---- 1. prepA1: W-pack (blocks 0,1) + per-block bucket histogram ----------

__global__ __launch_bounds__(256) void prepA1_kernel(
    const int* __restrict__ dst, const float* __restrict__ W1,
    const float* __restrict__ W2, unsigned* __restrict__ Wt1,
    unsigned* __restrict__ Wt2, int* __restrict__ histmat, int E)
{
    __shared__ int hist[256];
    int t = threadIdx.x;
    if (blockIdx.x == 0) {
        for (int f = t; f < 128 * 64; f += 256) {
            int c = f % 128, j = f / 128;
            Wt1[c * 64 + j] = bf16r(W1[(size_t)(2 * j) * 128 + c]) |
                              (bf16r(W1[(size_t)(2 * j + 1) * 128 + c]) << 16);
        }
        return;
    }
    if (blockIdx.x == 1) {
        for (int f = t; f < 64 * 64; f += 256) {
            int c = f % 64, j = f / 64;
            Wt2[c * 64 + j] = bf16r(W2[(size_t)(2 * j) * 64 + c]) |
                              (bf16r(W2[(size_t)(2 * j + 1) * 64 + c]) << 16);
        }
        return;
    }
    int blk = blockIdx.x - 2;
    hist[t] = 0;
    __syncthreads();
    int e0 = blk * CHUNK;
    int nv = min(CHUNK, E - e0);
#pragma unroll
    for (int j = 0; j < CHUNK / 256; ++j) {
        int idx = t + j * 256;
        if (idx < nv) atomicAdd(&hist[dst[e0 + idx] >> BSHIFT], 1);
    }
    __syncthreads();
    histmat[blk * 256 + t] = hist[t];
}

// ---- 2. scanB -------------------------------------------------------------

__global__ __launch_bounds__(256) void scanB_kernel(
    int* __restrict__ histmat, int* __restrict__ bucketSize, int NBLK)
{
    __shared__ int sums[256];
    int b = blockIdx.x, t = threadIdx.x;
    const int PER = (NBLK + 255) / 256;
    int loc[8];
    int s = 0;
#pragma unroll 8
    for (int j = 0; j < PER; ++j) {
        int r = t * PER + j;
        int v = (r < NBLK) ? histmat[r * 256 + b] : 0;
        loc[j] = v; s += v;
    }
    sums[t] = s;
    __syncthreads();
    int v = s;
#pragma unroll
    for (int off = 1; off < 256; off <<= 1) {
        int a = (t >= off) ? sums[t - off] : 0;
        __syncthreads();
        sums[t] += a;
        __syncthreads();
    }
    if (t == 255) bucketSize[b] = sums[255];
    int run = sums[t] - v;
#pragma unroll 8
    for (int j = 0; j < PER; ++j) {
        int r = t * PER + j;
        if (r < NBLK) { histmat[r * 256 + b] = run; run += loc[j]; }
    }
}

// ---- 3. a2 + gemm1 (raw h1 = x@W1, bf16-packed), fused dispatch -----------

#define A2G_SMEM 52224     // gemm: 64*68*4 + 128*68*4 ; a2 needs 25600

__device__ __forceinline__ void a2_body(
    char* smem, int blk,
    const int* __restrict__ src, const int* __restrict__ dst,
    const float* __restrict__ ew, const int* __restrict__ histmat,
    uint2* __restrict__ csrTmp, int E)
{
    int* hist = (int*)smem;
    int* sc   = hist + 256;
    int* exc  = sc + 256;
    int* lcur = exc + 256;
    int* basel= lcur + 256;
    uint2* ent = (uint2*)(basel + 256);
    unsigned short* bof = (unsigned short*)(ent + CHUNK);

    int t = threadIdx.x;
    hist[t] = 0; lcur[t] = 0;
    basel[t] = histmat[blk * 256 + t];
    __syncthreads();

    int e0 = blk * CHUNK;
    int nv = min(CHUNK, E - e0);
    int dv[CHUNK / 256]; int sv[CHUNK / 256]; unsigned wv[CHUNK / 256];
#pragma unroll
    for (int j = 0; j < CHUNK / 256; ++j) {
        int idx = t + j * 256;
        if (idx < nv) {
            int e = e0 + idx;
            dv[j] = dst[e]; sv[j] = src[e]; wv[j] = __float_as_uint(ew[e]);
            atomicAdd(&hist[dv[j] >> BSHIFT], 1);
        } else dv[j] = -1;
    }
    __syncthreads();
    int hv = hist[t];
    sc[t] = hv;
    __syncthreads();
#pragma unroll
    for (int off = 1; off < 256; off <<= 1) {
        int a = (t >= off) ? sc[t - off] : 0;
        __syncthreads();
        sc[t] += a;
        __syncthreads();
    }
    exc[t] = sc[t] - hv;
    __syncthreads();
#pragma unroll
    for (int j = 0; j < CHUNK / 256; ++j) {
        if (dv[j] >= 0) {
            int b  = dv[j] >> BSHIFT;
            int dl = dv[j] & (BNODES - 1);
            int p  = exc[b] + atomicAdd(&lcur[b], 1);
            ent[p] = make_uint2(((unsigned)dl << 17) | (unsigned)sv[j], wv[j]);
            bof[p] = (unsigned short)b;
        }
    }
    __syncthreads();
#pragma unroll
    for (int j = 0; j < CHUNK / 256; ++j) {
        int i = t + j * 256;
        if (i < nv) {
            int b = bof[i];
            csrTmp[(size_t)b * CAP + basel[b] + (i - exc[b])] = ent[i];
        }
    }
}

__device__ __forceinline__ void gemm1_body(
    char* smem, int blk, const float* __restrict__ Xf,
    const unsigned* __restrict__ Wt, unsigned* __restrict__ Hb, int M)
{
    constexpr int LW = 68, KU = 64;
    unsigned* sA = (unsigned*)smem;            // 64 x LW
    unsigned* sB = sA + 64 * LW;               // 128 x LW
    const int t = threadIdx.x;
    const int rbase = blk * 64;

    for (int f = t; f < 128 * 16; f += 256) {  // B: 128 rows x 16 uint4
        int c = f >> 4, qd = f & 15;
        *(uint4*)&sB[c * LW + qd * 4] = *(const uint4*)&Wt[c * KU + qd * 4];
    }
    for (int f = t; f < 64 * 32; f += 256) {   // A: fp32 -> bf16 pack
        int r = f >> 5, c4 = f & 31;
        int gr = rbase + r;
        float4 v = make_float4(0.f, 0.f, 0.f, 0.f);
        if (gr < M) v = *(const float4*)&Xf[(size_t)gr * 128 + c4 * 4];
        sA[r * LW + c4 * 2]     = bf16r(v.x) | (bf16r(v.y) << 16);
        sA[r * LW + c4 * 2 + 1] = bf16r(v.z) | (bf16r(v.w) << 16);
    }
    __syncthreads();

    const int wave = t >> 6, lane = t & 63;
    const int quad = lane >> 4, lr = lane & 15;
    const int n0 = wave * 32;

    f32x4 acc[4][2];
#pragma unroll
    for (int mi = 0; mi < 4; ++mi)
#pragma unroll
        for (int ni = 0; ni < 2; ++ni)
            acc[mi][ni] = (f32x4){0.f, 0.f, 0.f, 0.f};

#pragma unroll
    for (int ks = 0; ks < 4; ++ks) {
        int ko = ks * 16 + quad * 4;
        bf16x8 b0 = *(const bf16x8*)&sB[(n0 + lr) * LW + ko];
        bf16x8 b1 = *(const bf16x8*)&sB[(n0 + 16 + lr) * LW + ko];
#pragma unroll
        for (int mi = 0; mi < 4; ++mi) {
            bf16x8 a = *(const bf16x8*)&sA[(mi * 16 + lr) * LW + ko];
            acc[mi][0] = __builtin_amdgcn_mfma_f32_16x16x32_bf16(a, b0, acc[mi][0], 0, 0, 0);
            acc[mi][1] = __builtin_amdgcn_mfma_f32_16x16x32_bf16(a, b1, acc[mi][1], 0, 0, 0);
        }
    }
    __syncthreads();

    unsigned short* sO = (unsigned short*)sA;          // [64][2*LW]
#pragma unroll
    for (int mi = 0; mi < 4; ++mi)
#pragma unroll
        for (int ni = 0; ni < 2; ++ni)
#pragma unroll
            for (int r = 0; r < 4; ++r)
                sO[(mi * 16 + quad * 4 + r) * (2 * LW) + n0 + ni * 16 + lr] =
                    (unsigned short)bf16r(acc[mi][ni][r]);
    __syncthreads();

    for (int f = t; f < 64 * 64; f += 256) {
        int row = f >> 6, cu = f & 63;
        int gr = rbase + row;
        if (gr < M) Hb[(size_t)gr * 64 + cu] = sA[row * LW + cu];
    }
}

__global__ __launch_bounds__(256) void a2g_kernel(
    const int* __restrict__ src, const int* __restrict__ dst,
    const float* __restrict__ ew, const int* __restrict__ histmat,
    uint2* __restrict__ csrTmp, int E, int NBLK,
    const float* __restrict__ x, const unsigned* __restrict__ Wt1,
    unsigned* __restrict__ h1, int M)
{
    __shared__ __align__(16) char smem[A2G_SMEM];
    if ((int)blockIdx.x < NBLK)
        a2_body(smem, blockIdx.x, src, dst, ew, histmat, csrTmp, E);
    else
        gemm1_body(smem, blockIdx.x - NBLK, x, Wt1, h1, M);
}

// ---- 4. B1: per-bucket degree/count (LDS), dinv, nodeinfo -----------------

__global__ __launch_bounds__(1024) void b1_kernel(
    const uint2* __restrict__ csrTmp, const int* __restrict__ bucketSize,
    float* __restrict__ dinv, uint2* __restrict__ nodeinfo, int N)
{
    __shared__ unsigned long long dc[BNODES];
    __shared__ int scn[BNODES];
    int b = blockIdx.x, t = threadIdx.x;
    if (t < BNODES) dc[t] = 0ull;
    __syncthreads();

    int sz = min(bucketSize[b], CAP);
    const uint2* reg = csrTmp + (size_t)b * CAP;
    for (int i = t; i < sz; i += 1024) {
        uint2 en = reg[i];
        int dl = (int)(en.x >> 17);
        unsigned fx = (unsigned)__float2uint_rn(__uint_as_float(en.y) * 16777216.0f);
        atomicAdd(&dc[dl], (1ull << 32) | (unsigned long long)fx);
    }
    __syncthreads();

    int cnt = 0; float dv = 1.0f;
    if (t < BNODES) {
        unsigned long long v = dc[t];
        cnt = (int)(v >> 32);
        dv = rsqrtf((float)(unsigned)(v & 0xffffffffull) * (1.0f / 16777216.0f) + 1.0f);
        scn[t] = cnt;
    }
    __syncthreads();
#pragma unroll
    for (int off = 1; off < BNODES; off <<= 1) {
        int a = 0;
        if (t < BNODES && t >= off) a = scn[t - off];
        __syncthreads();
        if (t < BNODES) scn[t] += a;
        __syncthreads();
    }
    if (t < BNODES) {
        int excl = scn[t] - cnt;
        int gn = b * BNODES + t;
        if (gn < N) {
            dinv[gn] = dv;
            nodeinfo[gn] = make_uint2((unsigned)(b * CAP + excl), (unsigned)cnt);
        }
    }
}

// ---- 5. B2: per-bucket local sort + full weight w = dinv[s]*ew*dinv[d] ----

__global__ __launch_bounds__(1024) void b2_kernel(
    const uint2* __restrict__ csrTmp, const int* __restrict__ bucketSize,
    const uint2* __restrict__ nodeinfo, const float* __restrict__ dinv,
    uint2* __restrict__ csrF, int N)
{
    __shared__ float dinv_l[BNODES];
    __shared__ int beg[BNODES], cur[BNODES];
    int b = blockIdx.x, t = threadIdx.x;
    if (t < BNODES) {
        int gn = b * BNODES + t;
        float dv = 1.0f; int bg = 0;
        if (gn < N) { uint2 inf = nodeinfo[gn]; bg = (int)inf.x; dv = dinv[gn]; }
        dinv_l[t] = dv; beg[t] = bg; cur[t] = 0;
    }
    __syncthreads();

    int sz = min(bucketSize[b], CAP);
    const uint2* reg = csrTmp + (size_t)b * CAP;
    for (int i = t; i < sz; i += 1024) {
        uint2 en = reg[i];
        int dl = (int)(en.x >> 17);
        int s  = (int)(en.x & 0x1FFFFu);
        int p  = beg[dl] + atomicAdd(&cur[dl], 1);
        float w = dinv[s] * __uint_as_float(en.y) * dinv_l[dl];
        csrF[p] = make_uint2((unsigned)s, __float_as_uint(w));
    }
}

// ---- 6. gg: gather h1 (w-form) + bias/relu + MFMA gemm2 -> raw h2 ---------
// 1024 thr / 16 waves / 16 nodes (1 per wave).  Self-loop weight = dinv^2.

__global__ __launch_bounds__(1024) void gg_kernel(
    const uint2* __restrict__ nodeinfo, const uint2* __restrict__ csr,
    const uint4* __restrict__ Hb4,                 // h1 row = 16 uint4
    const float* __restrict__ dinv, const float* __restrict__ bias,
    const unsigned* __restrict__ Wt2, unsigned* __restrict__ H2, int N)
{
    __shared__ __align__(16) unsigned sG[16 * 68];   // g1 tile bf16-packed
    __shared__ __align__(16) float    sO[16 * 68];   // h2 fp32 tile

    const int t = threadIdx.x, wave = t >> 6, lane = t & 63;
    const int q = lane >> 4, cg = lane & 15;
    const int nb = blockIdx.x * 16;
    const int node = nb + wave;                      // 6250*16 == 100000

    {
        float di = dinv[node];
        float w0 = (q == 0) ? di * di : 0.f;         // self-loop weight
        float acc[8];
        {
            uint4 su = Hb4[(size_t)node * 16 + cg];
            acc[0] = bf_lo(su.x) * w0; acc[1] = bf_hi(su.x) * w0;
            acc[2] = bf_lo(su.y) * w0; acc[3] = bf_hi(su.y) * w0;
            acc[4] = bf_lo(su.z) * w0; acc[5] = bf_hi(su.z) * w0;
            acc[6] = bf_lo(su.w) * w0; acc[7] = bf_hi(su.w) * w0;
        }
        uint2 inf = nodeinfo[node];
        int beg = (int)inf.x, end = beg + (int)inf.y;
        for (int j = beg; j < end; j += 64) {
            int cs = 0; float cw = 0.f;
            if (j + lane < end) {
                uint2 p = csr[j + lane];
                cs = (int)p.x;
                cw = __uint_as_float(p.y);           // full precomputed weight
            }
            int mm = end - j; if (mm > 64) mm = 64;
#pragma unroll 4
            for (int k = 0; k < mm; k += 4) {
                int   s = __shfl(cs, k + q);
                float w = __shfl(cw, k + q);         // 0 beyond mm
                uint4 u = Hb4[(size_t)s * 16 + cg];
                acc[0] = fmaf(bf_lo(u.x), w, acc[0]); acc[1] = fmaf(bf_hi(u.x), w, acc[1]);
                acc[2] = fmaf(bf_lo(u.y), w, acc[2]); acc[3] = fmaf(bf_hi(u.y), w, acc[3]);
                acc[4] = fmaf(bf_lo(u.z), w, acc[4]); acc[5] = fmaf(bf_hi(u.z), w, acc[5]);
                acc[6] = fmaf(bf_lo(u.w), w, acc[6]); acc[7] = fmaf(bf_hi(u.w), w, acc[7]);
            }
        }
#pragma unroll
        for (int v = 0; v < 8; ++v) {
            acc[v] += __shfl_xor(acc[v], 16);
            acc[v] += __shfl_xor(acc[v], 32);
        }
        if (q == 0) {
            int c = cg * 8;
            uint4 pk;
            pk.x = bf16r(fmaxf(acc[0] + bias[c + 0], 0.f)) |
                   (bf16r(fmaxf(acc[1] + bias[c + 1], 0.f)) << 16);
            pk.y = bf16r(fmaxf(acc[2] + bias[c + 2], 0.f)) |
                   (bf16r(fmaxf(acc[3] + bias[c + 3], 0.f)) << 16);
            pk.z = bf16r(fmaxf(acc[4] + bias[c + 4], 0.f)) |
                   (bf16r(fmaxf(acc[5] + bias[c + 5], 0.f)) << 16);
            pk.w = bf16r(fmaxf(acc[6] + bias[c + 6], 0.f)) |
                   (bf16r(fmaxf(acc[7] + bias[c + 7], 0.f)) << 16);
            *(uint4*)&sG[wave * 68 + cg * 4] = pk;
        }
    }
    __syncthreads();

    // h2 tile: waves 0..3 each compute n-tile n0 = wave*16
    if (wave < 4) {
        const int quad = lane >> 4, lr = lane & 15;
        const int n0 = wave * 16;
        f32x4 accv = (f32x4){0.f, 0.f, 0.f, 0.f};
#pragma unroll
        for (int ks = 0; ks < 4; ++ks) {
            int ko = ks * 16 + quad * 4;
            bf16x8 av = *(const bf16x8*)&sG[lr * 68 + ko];
            bf16x8 bv = *(const bf16x8*)&Wt2[(n0 + lr) * 64 + ko];
            accv = __builtin_amdgcn_mfma_f32_16x16x32_bf16(av, bv, accv, 0, 0, 0);
        }
#pragma unroll
        for (int r = 0; r < 4; ++r)
            sO[(quad * 4 + r) * 68 + n0 + lr] = accv[r];
    }
    __syncthreads();

    if (t < 512) {                         // 16 rows x 32 packed uints
        int row = t >> 5, cu = t & 31;
        unsigned pk = bf16r(sO[row * 68 + 2 * cu]) |
                      (bf16r(sO[row * 68 + 2 * cu + 1]) << 16);
        H2[(size_t)(nb + row) * 32 + cu] = pk;
    }
}

// ---- 7. gather64: aggregate raw h2 (w-form) -> out fp32 -------------------

__global__ __launch_bounds__(256) void gather64_kernel(
    const uint2* __restrict__ nodeinfo, const uint2* __restrict__ csr,
    const uint4* __restrict__ Hb4,                 // h2 row = 8 uint4
    const float* __restrict__ dinv, const float* __restrict__ bias,
    float* __restrict__ OUT, int N)
{
    int node = blockIdx.x * 4 + (threadIdx.x >> 6);
    if (node >= N) return;
    int lane = threadIdx.x & 63;
    int q  = lane >> 3;        // slot 0..7
    int cg = lane & 7;

    float di = dinv[node];
    float w0 = (q == 0) ? di * di : 0.f;
    float acc[8];
    {
        uint4 su = Hb4[(size_t)node * 8 + cg];
        acc[0] = bf_lo(su.x) * w0; acc[1] = bf_hi(su.x) * w0;
        acc[2] = bf_lo(su.y) * w0; acc[3] = bf_hi(su.y) * w0;
        acc[4] = bf_lo(su.z) * w0; acc[5] = bf_hi(su.z) * w0;
        acc[6] = bf_lo(su.w) * w0; acc[7] = bf_hi(su.w) * w0;
    }

    uint2 inf = nodeinfo[node];
    int beg = (int)inf.x, end = beg + (int)inf.y;
    for (int j = beg; j < end; j += 64) {
        int cs = 0; float cw = 0.f;
        if (j + lane < end) {
            uint2 p = csr[j + lane];
            cs = (int)p.x;
            cw = __uint_as_float(p.y);             // full precomputed weight
        }
        int mm = end - j; if (mm > 64) mm = 64;
#pragma unroll 2
        for (int k = 0; k < mm; k += 8) {
            int   s = __shfl(cs, k + q);
            float w = __shfl(cw, k + q);
            uint4 u = Hb4[(size_t)s * 8 + cg];
            acc[0] = fmaf(bf_lo(u.x), w, acc[0]); acc[1] = fmaf(bf_hi(u.x), w, acc[1]);
            acc[2] = fmaf(bf_lo(u.y), w, acc[2]); acc[3] = fmaf(bf_hi(u.y), w, acc[3]);
            acc[4] = fmaf(bf_lo(u.z), w, acc[4]); acc[5] = fmaf(bf_hi(u.z), w, acc[5]);
            acc[6] = fmaf(bf_lo(u.w), w, acc[6]); acc[7] = fmaf(bf_hi(u.w), w, acc[7]);
        }
    }

#pragma unroll
    for (int v = 0; v < 8; ++v) {
        acc[v] += __shfl_xor(acc[v], 8);
        acc[v] += __shfl_xor(acc[v], 16);
        acc[v] += __shfl_xor(acc[v], 32);
    }

    int c = cg * 8 + q;
    OUT[(size_t)node * 64 + c] = acc[q] + bias[c];
}

static inline size_t align_up(size_t x) { return (x + 255) & ~size_t(255); }

extern "C" void kernel_launch(void* const* d_in, const int* in_sizes, int n_in,
                              void* d_out, int out_size, void* d_ws, size_t ws_size,
                              hipStream_t stream)
{
    const float* x  = (const float*)d_in[0];
    const int*   ei = (const int*)d_in[1];
    const float* ew = (const float*)d_in[2];
    const float* W1 = (const float*)d_in[3];
    const float* b1 = (const float*)d_in[4];
    const float* W2 = (const float*)d_in[5];
    const float* b2 = (const float*)d_in[6];
    float* out = (float*)d_out;

    const int N = N_NODES;
    const int E = in_sizes[2];
    const int* src = ei;
    const int* dst = ei + E;

    const int NBLK = (E + CHUNK - 1) / CHUNK;
    const size_t REGION = (size_t)NBUCK * CAP;
    const int GEMM1B = (N + 63) / 64;

    char* ws = (char*)d_ws;
    int*   histmat   = (int*)ws;   ws += align_up((size_t)NBLK * 256 * 4);
    int*   bucketSize= (int*)ws;   ws += align_up((size_t)NBUCK * 4);
    float* dinv      = (float*)ws; ws += align_up((size_t)N * 4);
    uint2* nodeinfo  = (uint2*)ws; ws += align_up((size_t)N * 8);
    uint2* csrTmp    = (uint2*)ws; ws += align_up(REGION * 8);
    uint2* csrF      = (uint2*)ws; ws += align_up(REGION * 8);
    unsigned* Wt1    = (unsigned*)ws; ws += align_up((size_t)128 * 64 * 4);
    unsigned* Wt2    = (unsigned*)ws; ws += align_up((size_t)64 * 64 * 4);
    unsigned* h1     = (unsigned*)ws; ws += align_up((size_t)N * 64 * 4);  // raw bf16 pk
    unsigned* h2     = (unsigned*)ws; ws += align_up((size_t)N * 32 * 4);  // raw bf16 pk

    prepA1_kernel<<<NBLK + 2, 256, 0, stream>>>(dst, W1, W2, Wt1, Wt2, histmat, E);
    scanB_kernel<<<NBUCK, 256, 0, stream>>>(histmat, bucketSize, NBLK);
    a2g_kernel<<<NBLK + GEMM1B, 256, 0, stream>>>(
        src, dst, ew, histmat, csrTmp, E, NBLK, x, Wt1, h1, N);
    b1_kernel<<<NBUCK, 1024, 0, stream>>>(csrTmp, bucketSize, dinv, nodeinfo, N);
    b2_kernel<<<NBUCK, 1024, 0, stream>>>(csrTmp, bucketSize, nodeinfo, dinv, csrF, N);
    gg_kernel<<<N / 16, 1024, 0, stream>>>(nodeinfo, csrF, (const uint4*)h1,
                                           dinv, b1, Wt2, h2, N);
    gather64_kernel<<<(N + 3) / 4, 256, 0, stream>>>(
        nodeinfo, csrF, (const uint4*)h2, dinv, b2, out, N);
}